// Round 5
// baseline (13999.271 us; speedup 1.0000x reference)
//
#include <hip/hip_runtime.h>

#define BS    32     // batches
#define M     256    // rows
#define N     512    // cols
#define ITERS 1000
#define WPB   8      // workgroups per batch
#define RPW   32     // rows per workgroup (M / WPB)
#define BLK   256    // threads per block
#define ALPHA 0.02f
#define BETA  0.02f

// LDS layout: 64-col chunks padded to 68 floats -> conflict-free b128 reads.
#define CH        68
#define ROWSTRIDE (8 * CH)            // 544 floats per row
#define A_FLOATS  (RPW * ROWSTRIDE)   // 17408
#define V_OFF     A_FLOATS
#define U_OFF     (A_FLOATS + ROWSTRIDE)
#define SMEM_FLOATS (U_OFF + RPW)

// Exchange buffer: [2][BS][256 colpairs][WPB] x 16B {val0,tag, val1,tag}.
// Per-thread read = 8 contiguous 16B units = 128 B. Each 8B word is a
// self-consistent (val,tag) pair, written/read as one relaxed agent-scope
// (sc1, MALL-coherent) atomic -> self-validating, no flag barrier needed.
#define PBYTES ((size_t)2 * BS * 256 * WPB * 16)

__device__ __forceinline__ int ldsidx(int r, int n) {
  return r * ROWSTRIDE + (n >> 6) * CH + (n & 63);
}

__device__ __forceinline__ unsigned long long ld_coh_u64(const void* p) {
  return __hip_atomic_load(reinterpret_cast<const unsigned long long*>(p),
                           __ATOMIC_RELAXED, __HIP_MEMORY_SCOPE_AGENT);
}
__device__ __forceinline__ void st_coh_u64(void* p, unsigned long long v) {
  __hip_atomic_store(reinterpret_cast<unsigned long long*>(p), v,
                     __ATOMIC_RELAXED, __HIP_MEMORY_SCOPE_AGENT);
}

__global__ __launch_bounds__(BLK, 1) void pdhg_kernel(
    const float* __restrict__ A, const float* __restrict__ Bvec,
    float* __restrict__ out, char* __restrict__ pb)
{
  __shared__ float smem[SMEM_FLOATS];
  const int tid   = threadIdx.x;
  const int bid   = blockIdx.x;
  const int batch = bid & (BS - 1);
  const int slice = bid >> 5;
  const int row0  = slice * RPW;

  // ---- stage A slice into LDS (padded layout), coalesced float4 ----
  const float* Ag = A + (size_t)batch * M * N + (size_t)row0 * N;
  for (int i = tid; i < RPW * N / 4; i += BLK) {
    int r = i >> 7;
    int n = (i & 127) << 2;
    float4 a = reinterpret_cast<const float4*>(Ag)[i];
    *reinterpret_cast<float4*>(&smem[ldsidx(r, n)]) = a;
  }

  const int   r    = tid >> 3;
  const int   l8   = tid & 7;
  const float breg = Bvec[batch * M + row0 + r];
  float u_reg = 0.0f;
  float x0 = 0.0f, x1 = 0.0f;
  const int n0 = 2 * tid;

  float* v_s = smem + V_OFF;
  float* u_s = smem + U_OFF;
  const int vb = (n0 >> 6) * CH + (n0 & 63);

  __syncthreads();   // staging visible

  for (int it = 0; it < ITERS; ++it) {
    const int buf = it & 1;
    const unsigned want = (unsigned)it;
    const char* rbase = pb + (((size_t)(buf * BS + batch) * 256 + tid) << 7);

    // ---- phase A: poll self-validating tagged partials (one MALL trip) ----
    unsigned long long q[16];
    for (;;) {
#pragma unroll
      for (int w = 0; w < 8; ++w) {
        q[2 * w]     = ld_coh_u64(rbase + 16 * w);
        q[2 * w + 1] = ld_coh_u64(rbase + 16 * w + 8);
      }
      unsigned bad = 0;
#pragma unroll
      for (int w = 0; w < 16; ++w)
        bad |= (unsigned)(q[w] >> 32) ^ want;
      if (!bad) break;
    }
    float t0 = 0.f, t1 = 0.f;
#pragma unroll
    for (int w = 0; w < 8; ++w) {
      t0 += __uint_as_float((unsigned)q[2 * w]);
      t1 += __uint_as_float((unsigned)q[2 * w + 1]);
    }

    float y0  = x0 - ALPHA * t0, y1 = x1 - ALPHA * t1;
    float xn0 = fmaxf(y0 - ALPHA, 0.f) - fmaxf(-y0 - ALPHA, 0.f);
    float xn1 = fmaxf(y1 - ALPHA, 0.f) - fmaxf(-y1 - ALPHA, 0.f);
    float v0  = 2.f * xn0 - x0, v1 = 2.f * xn1 - x1;
    x0 = xn0; x1 = xn1;

    if (it == ITERS - 1) break;

    *reinterpret_cast<float2*>(&v_s[vb]) = make_float2(v0, v1);
    __syncthreads();   // all phase-A polls done before any phase-B/C work

    // ---- phase B: row dots (A·v), u update (row-owned) ----
    float dot = 0.f;
    {
      const float4* A4 = reinterpret_cast<const float4*>(smem) +
                         (r * (ROWSTRIDE / 4) + l8 * (CH / 4));
      const float4* V4 = reinterpret_cast<const float4*>(v_s) + l8 * (CH / 4);
#pragma unroll
      for (int k = 0; k < 16; ++k) {
        float4 a  = A4[k];
        float4 vv = V4[k];
        dot += a.x * vv.x + a.y * vv.y + a.z * vv.z + a.w * vv.w;
      }
    }
    dot += __shfl_xor(dot, 1);
    dot += __shfl_xor(dot, 2);
    dot += __shfl_xor(dot, 4);
    u_reg += BETA * (dot - breg);
    if (l8 == 0) u_s[r] = u_reg;
    __syncthreads();

    // ---- phase C: partial p = A_slice^T u, publish tagged (one store) ----
    float us[RPW];
#pragma unroll
    for (int k = 0; k < RPW / 4; ++k) {
      float4 uu = reinterpret_cast<const float4*>(u_s)[k];
      us[4*k] = uu.x; us[4*k+1] = uu.y; us[4*k+2] = uu.z; us[4*k+3] = uu.w;
    }
    float p0 = 0.f, p1 = 0.f;
    const float2* A2 = reinterpret_cast<const float2*>(smem) + (vb >> 1);
#pragma unroll
    for (int rr = 0; rr < RPW; ++rr) {
      float2 a = A2[rr * (ROWSTRIDE / 2)];
      p0 += a.x * us[rr];
      p1 += a.y * us[rr];
    }
    const unsigned long long wtag64 = ((unsigned long long)(it + 1)) << 32;
    char* wb = pb + (((size_t)(((it + 1) & 1) * BS + batch) * 256 + tid) << 7) +
               (slice << 4);
    st_coh_u64(wb,     wtag64 | (unsigned long long)__float_as_uint(p0));
    st_coh_u64(wb + 8, wtag64 | (unsigned long long)__float_as_uint(p1));
    // Overwrite safety (no flag barrier): this store targets buffer (it+1)&1,
    // which holds tag-(it-1) data last read at iter it-1. Our phase-A poll at
    // iter `it` observed tag-`it` from every wg; those stores were issued
    // after each wg's post-phase-A barrier of iter it-1, i.e. after ALL its
    // threads' completed reads of buffer (it-1)&1. So no reader still needs
    // the data we overwrite.
  }

  // ---- epilogue: slice 0 writes x (all wgs hold identical x) ----
  if (slice == 0) {
    *reinterpret_cast<float2*>(out + (size_t)batch * N + n0) =
        make_float2(x0, x1);
  }
}

extern "C" void kernel_launch(void* const* d_in, const int* in_sizes, int n_in,
                              void* d_out, int out_size, void* d_ws, size_t ws_size,
                              hipStream_t stream) {
  const float* A = (const float*)d_in[0];
  const float* b = (const float*)d_in[1];
  float* out = (float*)d_out;
  char* pb = (char*)d_ws;                       // 2 MiB tagged exchange buffer

  hipMemsetAsync(d_ws, 0, PBYTES, stream);      // tag=0, val=0 for iter 0

  void* args[] = {(void*)&A, (void*)&b, (void*)&out, (void*)&pb};
  hipLaunchCooperativeKernel((const void*)pdhg_kernel, dim3(BS * WPB), dim3(BLK),
                             args, 0, stream);
}

// Round 6
// 2379.878 us; speedup vs baseline: 5.8823x; 5.8823x over previous
//
#include <hip/hip_runtime.h>

#define BS    32     // batches
#define M     256    // rows
#define N     512    // cols
#define ITERS 1000
#define WPB   8      // workgroups per batch
#define RPW   32     // rows per workgroup (M / WPB)
#define BLK   256    // threads per block
#define ALPHA 0.02f
#define BETA  0.02f

// LDS layout: 64-col chunks padded to 68 floats -> conflict-free b128 reads.
#define CH        68
#define ROWSTRIDE (8 * CH)            // 544 floats per row
#define A_FLOATS  (RPW * ROWSTRIDE)   // 17408
#define V_OFF     A_FLOATS
#define U_OFF     (A_FLOATS + ROWSTRIDE)
#define SMEM_FLOATS (U_OFF + RPW)

// Exchange buffer [2][BS][WPB][N] floats (writer-major, R2 layout: writers
// store lane-contiguous full 64B sectors; readers load 8B per slab).
// Tag lives in the LOW 8 MANTISSA BITS of every published float -> each 4B
// word is self-validating at any tearing granularity; no flag barrier, no
// separate tag bytes, no write amplification. Accuracy cost <= 2^-16 rel.
#define PBYTES ((size_t)2 * BS * WPB * N * 4)

__device__ __forceinline__ int ldsidx(int r, int n) {
  return r * ROWSTRIDE + (n >> 6) * CH + (n & 63);
}

__device__ __forceinline__ unsigned long long ld_coh_u64(const void* p) {
  return __hip_atomic_load(reinterpret_cast<const unsigned long long*>(p),
                           __ATOMIC_RELAXED, __HIP_MEMORY_SCOPE_AGENT);
}
__device__ __forceinline__ void st_coh_u64(void* p, unsigned long long v) {
  __hip_atomic_store(reinterpret_cast<unsigned long long*>(p), v,
                     __ATOMIC_RELAXED, __HIP_MEMORY_SCOPE_AGENT);
}

__device__ __forceinline__ unsigned tagf(float v, unsigned tag) {
  return (__float_as_uint(v) & ~0xFFu) | tag;
}

__global__ __launch_bounds__(BLK, 1) void pdhg_kernel(
    const float* __restrict__ A, const float* __restrict__ Bvec,
    float* __restrict__ out, float* __restrict__ pbuf)
{
  __shared__ float smem[SMEM_FLOATS];
  const int tid   = threadIdx.x;
  const int bid   = blockIdx.x;
  const int batch = bid & (BS - 1);
  const int slice = bid >> 5;
  const int row0  = slice * RPW;

  // ---- stage A slice into LDS (padded layout), coalesced float4 ----
  const float* Ag = A + (size_t)batch * M * N + (size_t)row0 * N;
  for (int i = tid; i < RPW * N / 4; i += BLK) {
    int r = i >> 7;
    int n = (i & 127) << 2;
    float4 a = reinterpret_cast<const float4*>(Ag)[i];
    *reinterpret_cast<float4*>(&smem[ldsidx(r, n)]) = a;
  }

  const int   r    = tid >> 3;
  const int   l8   = tid & 7;
  const float breg = Bvec[batch * M + row0 + r];
  float u_reg = 0.0f;
  float x0 = 0.0f, x1 = 0.0f;
  const int n0 = 2 * tid;

  float* v_s = smem + V_OFF;
  float* u_s = smem + U_OFF;
  const int vb = (n0 >> 6) * CH + (n0 & 63);

  __syncthreads();   // staging visible

  for (int it = 0; it < ITERS; ++it) {
    const int buf = it & 1;
    const unsigned want = (unsigned)it & 0xFFu;   // memset-0 == tag 0 == iter 0
    const float* pr = pbuf + ((size_t)(buf * BS + batch) * WPB) * N + n0;

    // ---- phase A: poll mantissa-tagged partials (steady-state: MALL hits) --
    unsigned long long q[8];
    for (;;) {
#pragma unroll
      for (int w = 0; w < 8; ++w) q[w] = ld_coh_u64(pr + w * N);
      unsigned bad = 0;
#pragma unroll
      for (int w = 0; w < 8; ++w) {
        bad |= ((unsigned)q[w] ^ want) & 0xFFu;
        bad |= ((unsigned)(q[w] >> 32) ^ want) & 0xFFu;
      }
      if (!bad) break;
    }
    float t0 = 0.f, t1 = 0.f;
#pragma unroll
    for (int w = 0; w < 8; ++w) {
      t0 += __uint_as_float((unsigned)q[w]);
      t1 += __uint_as_float((unsigned)(q[w] >> 32));
    }

    float y0  = x0 - ALPHA * t0, y1 = x1 - ALPHA * t1;
    float xn0 = fmaxf(y0 - ALPHA, 0.f) - fmaxf(-y0 - ALPHA, 0.f);
    float xn1 = fmaxf(y1 - ALPHA, 0.f) - fmaxf(-y1 - ALPHA, 0.f);
    float v0  = 2.f * xn0 - x0, v1 = 2.f * xn1 - x1;
    x0 = xn0; x1 = xn1;

    if (it == ITERS - 1) break;

    *reinterpret_cast<float2*>(&v_s[vb]) = make_float2(v0, v1);
    __syncthreads();   // all phase-A polls done before any phase-B/C work

    // ---- phase B: row dots (A·v), u update (row-owned) ----
    float dot = 0.f;
    {
      const float4* A4 = reinterpret_cast<const float4*>(smem) +
                         (r * (ROWSTRIDE / 4) + l8 * (CH / 4));
      const float4* V4 = reinterpret_cast<const float4*>(v_s) + l8 * (CH / 4);
#pragma unroll
      for (int k = 0; k < 16; ++k) {
        float4 a  = A4[k];
        float4 vv = V4[k];
        dot += a.x * vv.x + a.y * vv.y + a.z * vv.z + a.w * vv.w;
      }
    }
    dot += __shfl_xor(dot, 1);
    dot += __shfl_xor(dot, 2);
    dot += __shfl_xor(dot, 4);
    u_reg += BETA * (dot - breg);
    if (l8 == 0) u_s[r] = u_reg;
    __syncthreads();

    // ---- phase C: partial p = A_slice^T u, publish with mantissa tag ----
    float us[RPW];
#pragma unroll
    for (int k = 0; k < RPW / 4; ++k) {
      float4 uu = reinterpret_cast<const float4*>(u_s)[k];
      us[4*k] = uu.x; us[4*k+1] = uu.y; us[4*k+2] = uu.z; us[4*k+3] = uu.w;
    }
    float p0 = 0.f, p1 = 0.f;
    const float2* A2 = reinterpret_cast<const float2*>(smem) + (vb >> 1);
#pragma unroll
    for (int rr = 0; rr < RPW; ++rr) {
      float2 a = A2[rr * (ROWSTRIDE / 2)];
      p0 += a.x * us[rr];
      p1 += a.y * us[rr];
    }
    const unsigned wtag = (unsigned)(it + 1) & 0xFFu;
    const unsigned long long payload =
        (unsigned long long)tagf(p0, wtag) |
        ((unsigned long long)tagf(p1, wtag) << 32);
    // writer-major: this wg's 256 threads store 2KB contiguous -> full sectors
    st_coh_u64(pbuf + ((size_t)(((it + 1) & 1) * BS + batch) * WPB + slice) * N
                    + n0,
               payload);
    // Overwrite safety: store targets buffer (it+1)&1, last fully read at
    // iter it-1; our successful poll of tag-`it` from every wg implies every
    // wg passed its post-poll barrier of iter it-1, i.e. finished all reads
    // of that buffer. ABA: stale tag differs by 2 mod 256, never matches.
  }

  // ---- epilogue: slice 0 writes x (all wgs hold identical x) ----
  if (slice == 0) {
    *reinterpret_cast<float2*>(out + (size_t)batch * N + n0) =
        make_float2(x0, x1);
  }
}

extern "C" void kernel_launch(void* const* d_in, const int* in_sizes, int n_in,
                              void* d_out, int out_size, void* d_ws, size_t ws_size,
                              hipStream_t stream) {
  const float* A = (const float*)d_in[0];
  const float* b = (const float*)d_in[1];
  float* out = (float*)d_out;
  float* pbuf = (float*)d_ws;                   // 1 MiB tagged exchange buffer

  hipMemsetAsync(d_ws, 0, PBYTES, stream);      // tag=0, val=0 for iter 0

  void* args[] = {(void*)&A, (void*)&b, (void*)&out, (void*)&pbuf};
  hipLaunchCooperativeKernel((const void*)pdhg_kernel, dim3(BS * WPB), dim3(BLK),
                             args, 0, stream);
}

// Round 7
// 2231.702 us; speedup vs baseline: 6.2729x; 1.0664x over previous
//
#include <hip/hip_runtime.h>

#define BS    32
#define MDIM  256
#define NDIM  512
#define ITERS 1000
#define WPB   8      // wgs per batch; each owns 64 components of x/t
#define BLK   256
#define ALPHA 0.02f
#define BETA  0.02f

// ---- LDS layout (floats) ----
// A-tile (prologue only): 32 j-blocks of [32 rows x 16 cols] padded +4
#define ATS        516                  // A-tile block stride
#define ATILE_FL   (32 * ATS)           // 16512
#define WBUF_OFF   ATILE_FL             // w staged: 32 blocks x 20 (pad 4)
#define WBLK       20
#define P_OFF      (WBUF_OFF + 32 * WBLK)   // partials p[64][32]
#define C_OFF      (P_OFF + 64 * 32)        // c slice [64]
#define BT_OFF     (C_OFF + 64)             // b tile [32]
#define SMEM_FL    (BT_OFF + 32)            // ~77 KB

// Exchange slab: [2 parity][BS][512] floats, writer-major (each wg owns a
// contiguous 256B slot = full sectors). Values mantissa-tagged (low 8 bits
// = (k+1)&255): every 4B word self-validates; parity + tag-distance-2 mod
// 256 makes ABA impossible (proven R6).
#define SLAB_FL   (2 * BS * NDIM)

__device__ __forceinline__ unsigned long long ld_coh_u64(const void* p) {
  return __hip_atomic_load(reinterpret_cast<const unsigned long long*>(p),
                           __ATOMIC_RELAXED, __HIP_MEMORY_SCOPE_AGENT);
}
__device__ __forceinline__ void st_coh_u32(void* p, unsigned v) {
  __hip_atomic_store(reinterpret_cast<unsigned*>(p), v,
                     __ATOMIC_RELAXED, __HIP_MEMORY_SCOPE_AGENT);
}
__device__ __forceinline__ unsigned tagf(float v, unsigned tag) {
  return (__float_as_uint(v) & ~0xFFu) | tag;
}

__global__ __launch_bounds__(BLK, 1) void pdhg_kernel(
    const float* __restrict__ A, const float* __restrict__ Bvec,
    float* __restrict__ out, float* __restrict__ slab)
{
  __shared__ float smem[SMEM_FL];
  const int tid   = threadIdx.x;
  const int bid   = blockIdx.x;
  const int batch = bid & (BS - 1);
  const int slice = bid >> 5;
  const int i0    = slice * 64;        // this wg's x/t components

  const int tj = tid & 31;             // j-block [tj*16, +16)
  const int ti = tid >> 5;             // i-block [i0+ti*8, +8)

  // ================= PROLOGUE: G = A^T A slice (regs), c = A^T b ==========
  float acc[8][16];
#pragma unroll
  for (int r = 0; r < 8; ++r)
#pragma unroll
    for (int s = 0; s < 16; ++s) acc[r][s] = 0.f;
  float cacc[8];
#pragma unroll
  for (int r = 0; r < 8; ++r) cacc[r] = 0.f;

  const float* Ag = A + (size_t)batch * MDIM * NDIM;

  for (int mt = 0; mt < MDIM / 32; ++mt) {
    // stage A[mt*32..+32, :] into block-j LDS layout (coalesced float4)
#pragma unroll 4
    for (int q = 0; q < 16; ++q) {
      int f  = q * 256 + tid;          // float4 index in 32x512 tile
      int mm = f >> 7;
      int j  = (f & 127) << 2;
      float4 v = *reinterpret_cast<const float4*>(
          Ag + (size_t)(mt * 32 + mm) * NDIM + j);
      *reinterpret_cast<float4*>(
          &smem[(j >> 4) * ATS + mm * 16 + (j & 15)]) = v;
    }
    if (tid < 32) smem[BT_OFF + tid] = Bvec[batch * MDIM + mt * 32 + tid];
    __syncthreads();

    const int ibase = ((i0 + 8 * ti) >> 4) * ATS + ((8 * ti) & 15);
    const int jbase = tj * ATS;
    for (int mm = 0; mm < 32; ++mm) {
      float4 a0 = *reinterpret_cast<const float4*>(&smem[ibase + mm * 16]);
      float4 a1 = *reinterpret_cast<const float4*>(&smem[ibase + mm * 16 + 4]);
      float ai[8] = {a0.x, a0.y, a0.z, a0.w, a1.x, a1.y, a1.z, a1.w};
      float aj[16];
#pragma unroll
      for (int kk = 0; kk < 4; ++kk) {
        float4 v = *reinterpret_cast<const float4*>(
            &smem[jbase + mm * 16 + 4 * kk]);
        aj[4*kk] = v.x; aj[4*kk+1] = v.y; aj[4*kk+2] = v.z; aj[4*kk+3] = v.w;
      }
#pragma unroll
      for (int r = 0; r < 8; ++r)
#pragma unroll
        for (int s = 0; s < 16; ++s) acc[r][s] = fmaf(ai[r], aj[s], acc[r][s]);
      if (tj == 0) {
        float bv = smem[BT_OFF + mm];
#pragma unroll
        for (int r = 0; r < 8; ++r) cacc[r] = fmaf(ai[r], bv, cacc[r]);
      }
    }
    __syncthreads();   // before restaging next tile
  }
  if (tj == 0) {
#pragma unroll
    for (int r = 0; r < 8; ++r) smem[C_OFF + ti * 8 + r] = cacc[r];
  }
  __syncthreads();

  // ================= ITERATION ============================================
  const int  lane    = tid & 63;
  const int  wave    = tid >> 6;
  const bool owner   = (tid & 3) == 0;
  const int  i_own   = wave * 16 + (lane >> 2);   // == tid>>2 for owners
  const float c_reg  = smem[C_OFF + i_own];
  float x = 0.f, t = 0.f;

  float* myslot = slab + batch * NDIM + i0 + i_own;   // + parity*BS*NDIM
  const float* myrd = slab + batch * NDIM + 2 * tid;  // thread's 8B of w

  for (int k = 0; k < ITERS; ++k) {
    // x-update (owners; replicas not needed — each i owned by one lane)
    float xn = 0.f;
    if (owner) {
      float y = x - ALPHA * t;
      xn = fmaxf(y - ALPHA, 0.f) - fmaxf(-y - ALPHA, 0.f);
    }
    if (k == ITERS - 1) { x = xn; break; }

    const int par = (k & 1) * BS * NDIM;
    const unsigned tag = (unsigned)(k + 1) & 0xFFu;
    if (owner) {
      float wv = 2.f * xn - x;
      x = xn;
      st_coh_u32(myslot + par, tagf(wv, tag));
    }

    // poll full w (all 8 slots incl. own), 8B per thread, self-validating
    unsigned long long qq;
    do {
      qq = ld_coh_u64(myrd + par);
    } while ((((unsigned)qq ^ tag) & 0xFFu) |
             (((unsigned)(qq >> 32) ^ tag) & 0xFFu));

    // stage w into padded LDS (global j = 2*tid)
    {
      int j = 2 * tid;
      *reinterpret_cast<float2*>(&smem[WBUF_OFF + (j >> 4) * WBLK + (j & 15)]) =
          make_float2(__uint_as_float((unsigned)qq),
                      __uint_as_float((unsigned)(qq >> 32)));
    }
    __syncthreads();

    // G·w partials from register-resident G
    float wv[16];
    {
      const float* wb = &smem[WBUF_OFF + tj * WBLK];
#pragma unroll
      for (int kk = 0; kk < 4; ++kk) {
        float4 v = *reinterpret_cast<const float4*>(wb + 4 * kk);
        wv[4*kk] = v.x; wv[4*kk+1] = v.y; wv[4*kk+2] = v.z; wv[4*kk+3] = v.w;
      }
    }
#pragma unroll
    for (int r = 0; r < 8; ++r) {
      float p = 0.f;
#pragma unroll
      for (int s = 0; s < 16; ++s) p = fmaf(acc[r][s], wv[s], p);
      smem[P_OFF + (ti * 8 + r) * 32 + tj] = p;
    }
    __syncthreads();

    // reduce 32 partials per i: 4 threads/i read 8 each + 2 shuffles
    {
      int ired = tid >> 2, prt = tid & 3;
      const float* pp = &smem[P_OFF + ired * 32 + prt * 8];
      float4 pa = *reinterpret_cast<const float4*>(pp);
      float4 pb = *reinterpret_cast<const float4*>(pp + 4);
      float s8 = (pa.x + pa.y) + (pa.z + pa.w) +
                 (pb.x + pb.y) + (pb.z + pb.w);
      s8 += __shfl_xor(s8, 1);
      s8 += __shfl_xor(s8, 2);
      if (owner) t += BETA * (s8 - c_reg);   // t_{k+1} = t_k + β(Gw − c)
    }
  }

  // ---- epilogue: owners write x slice ----
  if (owner) out[(size_t)batch * NDIM + i0 + i_own] = x;
}

extern "C" void kernel_launch(void* const* d_in, const int* in_sizes, int n_in,
                              void* d_out, int out_size, void* d_ws, size_t ws_size,
                              hipStream_t stream) {
  const float* A = (const float*)d_in[0];
  const float* b = (const float*)d_in[1];
  float* out  = (float*)d_out;
  float* slab = (float*)d_ws;                    // 128 KiB w-exchange slab

  hipMemsetAsync(d_ws, 0, SLAB_FL * sizeof(float), stream);  // tag 0 ≠ 1,2

  void* args[] = {(void*)&A, (void*)&b, (void*)&out, (void*)&slab};
  hipLaunchCooperativeKernel((const void*)pdhg_kernel, dim3(BS * WPB), dim3(BLK),
                             args, 0, stream);
}

// Round 9
// 1552.657 us; speedup vs baseline: 9.0163x; 1.4373x over previous
//
#include <hip/hip_runtime.h>

#define BS    32
#define MDIM  256
#define NDIM  512
#define ITERS 1000
#define WPB   4      // wgs per batch; each owns 128 components of x/t
#define RPW   128    // rows of G per wg
#define BLK   512
#define ALPHA 0.02f
#define BETA  0.02f

// ---- LDS layout (floats) ----
#define ATS        516                  // A-tile block stride (prologue)
#define ATILE_FL   (32 * ATS)           // 16512
#define WBUF_OFF   ATILE_FL             // w staged: 32 blocks x 20 (pad 4)
#define WBLK       20
#define P_OFF      (WBUF_OFF + 32 * WBLK)   // partials p[128][32]
#define C_OFF      (P_OFF + RPW * 32)       // c slice [128]
#define BT_OFF     (C_OFF + RPW)            // b tile [32]
#define SMEM_FL    (BT_OFF + 32)            // ~86 KB

// Exchange slab: [2 parity][BS][512] floats, writer-major (each wg owns a
// contiguous 512B slot = full sectors). Mantissa-tagged (low 8 bits =
// (k+1)&255): every 4B word self-validates (proven R6/R7). Agent-scope sc1
// relaxed atomics only — no same-XCD fast path (R4/R8 post-mortem).
#define SLAB_FL   (2 * BS * NDIM)

__device__ __forceinline__ unsigned ld_coh_u32(const void* p) {
  return __hip_atomic_load(reinterpret_cast<const unsigned*>(p),
                           __ATOMIC_RELAXED, __HIP_MEMORY_SCOPE_AGENT);
}
__device__ __forceinline__ void st_coh_u32(void* p, unsigned v) {
  __hip_atomic_store(reinterpret_cast<unsigned*>(p), v,
                     __ATOMIC_RELAXED, __HIP_MEMORY_SCOPE_AGENT);
}
__device__ __forceinline__ unsigned tagf(float v, unsigned tag) {
  return (__float_as_uint(v) & ~0xFFu) | tag;
}

__global__ __launch_bounds__(BLK, 1) void pdhg_kernel(
    const float* __restrict__ A, const float* __restrict__ Bvec,
    float* __restrict__ out, float* __restrict__ slab)
{
  __shared__ float smem[SMEM_FL];
  const int tid   = threadIdx.x;
  const int bid   = blockIdx.x;
  const int batch = bid & (BS - 1);
  const int slice = bid >> 5;          // 0..3
  const int i0    = slice * RPW;       // this wg's x/t components

  const int tj = tid & 31;             // j-block [tj*16, +16)
  const int ti = tid >> 5;             // i-block [i0+ti*8, +8), ti in [0,16)

  // ================= PROLOGUE: G = A^T A slice (regs), c = A^T b ==========
  float acc[8][16];
#pragma unroll
  for (int r = 0; r < 8; ++r)
#pragma unroll
    for (int s = 0; s < 16; ++s) acc[r][s] = 0.f;
  float cacc[8];
#pragma unroll
  for (int r = 0; r < 8; ++r) cacc[r] = 0.f;

  const float* Ag = A + (size_t)batch * MDIM * NDIM;

  for (int mt = 0; mt < MDIM / 32; ++mt) {
    // stage A[mt*32..+32, :] into block-j LDS layout (coalesced float4)
#pragma unroll 4
    for (int q = 0; q < 8; ++q) {
      int f  = q * 512 + tid;          // float4 index in 32x512 tile
      int mm = f >> 7;
      int j  = (f & 127) << 2;
      float4 v = *reinterpret_cast<const float4*>(
          Ag + (size_t)(mt * 32 + mm) * NDIM + j);
      *reinterpret_cast<float4*>(
          &smem[(j >> 4) * ATS + mm * 16 + (j & 15)]) = v;
    }
    if (tid < 32) smem[BT_OFF + tid] = Bvec[batch * MDIM + mt * 32 + tid];
    __syncthreads();

    const int ibase = ((i0 + 8 * ti) >> 4) * ATS + ((8 * ti) & 15);
    const int jbase = tj * ATS;
    for (int mm = 0; mm < 32; ++mm) {
      float4 a0 = *reinterpret_cast<const float4*>(&smem[ibase + mm * 16]);
      float4 a1 = *reinterpret_cast<const float4*>(&smem[ibase + mm * 16 + 4]);
      float ai[8] = {a0.x, a0.y, a0.z, a0.w, a1.x, a1.y, a1.z, a1.w};
      float aj[16];
#pragma unroll
      for (int kk = 0; kk < 4; ++kk) {
        float4 v = *reinterpret_cast<const float4*>(
            &smem[jbase + mm * 16 + 4 * kk]);
        aj[4*kk] = v.x; aj[4*kk+1] = v.y; aj[4*kk+2] = v.z; aj[4*kk+3] = v.w;
      }
#pragma unroll
      for (int r = 0; r < 8; ++r)
#pragma unroll
        for (int s = 0; s < 16; ++s) acc[r][s] = fmaf(ai[r], aj[s], acc[r][s]);
      if (tj == 0) {
        float bv = smem[BT_OFF + mm];
#pragma unroll
        for (int r = 0; r < 8; ++r) cacc[r] = fmaf(ai[r], bv, cacc[r]);
      }
    }
    __syncthreads();
  }
  if (tj == 0) {
#pragma unroll
    for (int r = 0; r < 8; ++r) smem[C_OFF + ti * 8 + r] = cacc[r];
  }
  __syncthreads();

  // ================= ITERATION ============================================
  const bool owner   = (tid & 3) == 0;
  const int  i_own   = tid >> 2;                 // 0..127 (owners)
  const float c_reg  = smem[C_OFF + i_own];
  float x = 0.f, t = 0.f;

  float* myslot = slab + batch * NDIM + i0 + i_own;   // + parity*BS*NDIM
  const float* myrd = slab + batch * NDIM + tid;      // thread's 4B of w

  for (int k = 0; k < ITERS; ++k) {
    float xn = 0.f;
    if (owner) {
      float y = x - ALPHA * t;
      xn = fmaxf(y - ALPHA, 0.f) - fmaxf(-y - ALPHA, 0.f);
    }
    if (k == ITERS - 1) { x = xn; break; }

    const int par = (k & 1) * BS * NDIM;
    const unsigned tag = (unsigned)(k + 1) & 0xFFu;
    if (owner) {
      float wv = 2.f * xn - x;
      x = xn;
      st_coh_u32(myslot + par, tagf(wv, tag));
    }

    // poll this thread's 4B of w (self-validating mantissa tag)
    unsigned qq;
    do {
      qq = ld_coh_u32(myrd + par);
    } while ((qq ^ tag) & 0xFFu);

    // stage w into padded LDS (global j = tid)
    smem[WBUF_OFF + (tid >> 4) * WBLK + (tid & 15)] = __uint_as_float(qq);
    __syncthreads();

    // G·w partials from register-resident G
    float wv[16];
    {
      const float* wb = &smem[WBUF_OFF + tj * WBLK];
#pragma unroll
      for (int kk = 0; kk < 4; ++kk) {
        float4 v = *reinterpret_cast<const float4*>(wb + 4 * kk);
        wv[4*kk] = v.x; wv[4*kk+1] = v.y; wv[4*kk+2] = v.z; wv[4*kk+3] = v.w;
      }
    }
#pragma unroll
    for (int r = 0; r < 8; ++r) {
      float p = 0.f;
#pragma unroll
      for (int s = 0; s < 16; ++s) p = fmaf(acc[r][s], wv[s], p);
      smem[P_OFF + (ti * 8 + r) * 32 + tj] = p;
    }
    __syncthreads();

    // reduce 32 partials per i: 4 threads/i read 8 each + 2 shuffles
    {
      int ired = tid >> 2, prt = tid & 3;
      const float* pp = &smem[P_OFF + ired * 32 + prt * 8];
      float4 pa = *reinterpret_cast<const float4*>(pp);
      float4 pb = *reinterpret_cast<const float4*>(pp + 4);
      float s8 = (pa.x + pa.y) + (pa.z + pa.w) +
                 (pb.x + pb.y) + (pb.z + pb.w);
      s8 += __shfl_xor(s8, 1);
      s8 += __shfl_xor(s8, 2);
      if (owner) t += BETA * (s8 - c_reg);   // t_{k+1} = t_k + β(Gw − c)
    }
  }

  // ---- epilogue: owners write x slice ----
  if (owner) out[(size_t)batch * NDIM + i0 + i_own] = x;
}

extern "C" void kernel_launch(void* const* d_in, const int* in_sizes, int n_in,
                              void* d_out, int out_size, void* d_ws, size_t ws_size,
                              hipStream_t stream) {
  const float* A = (const float*)d_in[0];
  const float* b = (const float*)d_in[1];
  float* out  = (float*)d_out;
  float* slab = (float*)d_ws;                    // 128 KiB w-exchange slab

  hipMemsetAsync(d_ws, 0, SLAB_FL * sizeof(float), stream);  // tag 0 ≠ 1,2

  void* args[] = {(void*)&A, (void*)&b, (void*)&out, (void*)&slab};
  hipLaunchCooperativeKernel((const void*)pdhg_kernel, dim3(BS * WPB), dim3(BLK),
                             args, 0, stream);
}